// Round 1
// baseline (284.540 us; speedup 1.0000x reference)
//
#include <hip/hip_runtime.h>

#define NIN 32
#define NU  128
#define RPB 8            // batch rows per block
#define UNFOLDS 6
#define LOG2E 1.44269504088896340736f

// block = 256 threads: j = tid & 127 (unit), h = tid >> 7 (i-range half).
// One block handles RPB=8 consecutive batch rows; v[i] per row staged in LDS
// with [i][r] layout so per-i reads are wave-uniform broadcasts.
__global__ __launch_bounds__(256, 4)
void wormnet_kernel(const float* __restrict__ inputs,   // [B,32]
                    const float* __restrict__ state,    // [B,128]
                    const float* __restrict__ smu,      // [32,128]
                    const float* __restrict__ ssig,
                    const float* __restrict__ sW,
                    const float* __restrict__ serev,
                    const float* __restrict__ rmu,      // [128,128]
                    const float* __restrict__ rsig,
                    const float* __restrict__ rW,
                    const float* __restrict__ rerev,
                    const float* __restrict__ vleak,    // [128]
                    const float* __restrict__ gleak,
                    const float* __restrict__ cm_t,
                    const float* __restrict__ in_w,     // [32]
                    const float* __restrict__ in_b,
                    const float* __restrict__ out_w,    // [1]
                    const float* __restrict__ out_b,
                    float* __restrict__ out_y,          // [B]
                    float* __restrict__ out_v)          // [B,128]
{
    __shared__ float xs[NIN * RPB];   // xs[i*RPB + r]
    __shared__ float vs[NU * RPB];    // vs[i*RPB + r]
    __shared__ float num1[NU * RPB];  // h=1 partial num
    __shared__ float den1[NU * RPB];  // h=1 partial den

    const int tid  = threadIdx.x;
    const int j    = tid & (NU - 1);
    const int h    = tid >> 7;          // 0 or 1, uniform per wave
    const int base = blockIdx.x * RPB;  // first batch row of this block

    // ---- stage x = inputs*in_w + in_b into LDS (32i x 8r = 256 vals) ----
    {
        int i = tid & (NIN - 1);
        int r = tid >> 5;               // 0..7
        float x = inputs[(base + r) * NIN + i] * in_w[i] + in_b[i];
        xs[i * RPB + r] = x;
    }
    // ---- stage initial v into LDS (128i x 8r = 1024 vals, 4 per thread) ----
    {
        int jj = tid & (NU - 1);
        int rr = tid >> 7;              // 0..1
        #pragma unroll
        for (int k = 0; k < 4; ++k) {
            int r = rr + 2 * k;
            vs[jj * RPB + r] = state[(base + r) * NU + jj];
        }
    }
    __syncthreads();

    // ---- sensory sums: this thread's partial over i in [h*16, h*16+16) ----
    float numS[RPB], denS[RPB];
    #pragma unroll
    for (int r = 0; r < RPB; ++r) { numS[r] = 0.0f; denS[r] = 0.0f; }
    {
        const int i0 = h * (NIN / 2);
        #pragma unroll 2
        for (int ii = 0; ii < NIN / 2; ++ii) {
            const int i = i0 + ii;
            const float m  = smu [i * NU + j];
            const float sg = ssig[i * NU + j];
            const float Wv = sW  [i * NU + j];
            const float er = serev[i * NU + j];
            const float s2  = -LOG2E * sg;   // exp(-z) = 2^(s2*v + sm2)
            const float sm2 = -s2 * m;
            const float We  = Wv * er;
            #pragma unroll
            for (int r = 0; r < RPB; ++r) {
                float t = __builtin_fmaf(s2, xs[i * RPB + r], sm2);
                float e = __builtin_amdgcn_exp2f(t);
                float sgm = __builtin_amdgcn_rcpf(1.0f + e);
                numS[r] = __builtin_fmaf(We, sgm, numS[r]);
                denS[r] = __builtin_fmaf(Wv, sgm, denS[r]);
            }
        }
    }

    // ---- per-unit constants + vold registers (h==0 threads own unit j) ----
    float cm = 0.0f, glvl = 0.0f, cg = 0.0f;
    float vold[RPB];
    #pragma unroll
    for (int r = 0; r < RPB; ++r) vold[r] = 0.0f;
    if (h == 0) {
        cm = cm_t[j];
        float gl = gleak[j];
        glvl = gl * vleak[j];
        cg = cm + gl;
        #pragma unroll
        for (int r = 0; r < RPB; ++r) vold[r] = vs[j * RPB + r];
    }

    // ---- 6 semi-implicit unfolds ----
    for (int u = 0; u < UNFOLDS; ++u) {
        float num[RPB], den[RPB];
        #pragma unroll
        for (int r = 0; r < RPB; ++r) { num[r] = numS[r]; den[r] = denS[r]; }

        const int i0 = h * (NU / 2);
        #pragma unroll 2
        for (int ii = 0; ii < NU / 2; ++ii) {
            const int i = i0 + ii;
            const float m  = rmu [i * NU + j];
            const float sg = rsig[i * NU + j];
            const float Wv = rW  [i * NU + j];
            const float er = rerev[i * NU + j];
            const float s2  = -LOG2E * sg;
            const float sm2 = -s2 * m;
            const float We  = Wv * er;
            #pragma unroll
            for (int r = 0; r < RPB; ++r) {
                float t = __builtin_fmaf(s2, vs[i * RPB + r], sm2);
                float e = __builtin_amdgcn_exp2f(t);
                float sgm = __builtin_amdgcn_rcpf(1.0f + e);
                num[r] = __builtin_fmaf(We, sgm, num[r]);
                den[r] = __builtin_fmaf(Wv, sgm, den[r]);
            }
        }

        if (h == 1) {
            #pragma unroll
            for (int r = 0; r < RPB; ++r) {
                num1[j * RPB + r] = num[r];
                den1[j * RPB + r] = den[r];
            }
        }
        __syncthreads();
        if (h == 0) {
            #pragma unroll
            for (int r = 0; r < RPB; ++r) {
                float tn = num[r] + num1[j * RPB + r];
                float td = den[r] + den1[j * RPB + r];
                float vn = (__builtin_fmaf(cm, vold[r], glvl) + tn)
                           * __builtin_amdgcn_rcpf(cg + td);
                vold[r] = vn;
                vs[j * RPB + r] = vn;
            }
        }
        __syncthreads();
    }

    // ---- epilogue: write v and mapped outputs ----
    if (h == 0) {
        #pragma unroll
        for (int r = 0; r < RPB; ++r) {
            out_v[(base + r) * NU + j] = vold[r];
        }
        if (j == 0) {
            const float ow = out_w[0], ob = out_b[0];
            #pragma unroll
            for (int r = 0; r < RPB; ++r) {
                out_y[base + r] = vold[r] * ow + ob;
            }
        }
    }
}

extern "C" void kernel_launch(void* const* d_in, const int* in_sizes, int n_in,
                              void* d_out, int out_size, void* d_ws, size_t ws_size,
                              hipStream_t stream) {
    const float* inputs  = (const float*)d_in[0];
    const float* state   = (const float*)d_in[1];
    const float* smu     = (const float*)d_in[2];
    const float* ssig    = (const float*)d_in[3];
    const float* sW      = (const float*)d_in[4];
    const float* serev   = (const float*)d_in[5];
    const float* rmu     = (const float*)d_in[6];
    const float* rsig    = (const float*)d_in[7];
    const float* rW      = (const float*)d_in[8];
    const float* rerev   = (const float*)d_in[9];
    const float* vleak   = (const float*)d_in[10];
    const float* gleak   = (const float*)d_in[11];
    const float* cm_t    = (const float*)d_in[12];
    const float* in_w    = (const float*)d_in[13];
    const float* in_b    = (const float*)d_in[14];
    const float* out_w   = (const float*)d_in[15];
    const float* out_b   = (const float*)d_in[16];

    const int batch = in_sizes[1] / NU;        // 8192
    float* out_y = (float*)d_out;              // [batch]
    float* out_v = (float*)d_out + batch;      // [batch,128]

    dim3 grid(batch / RPB), block(256);
    hipLaunchKernelGGL(wormnet_kernel, grid, block, 0, stream,
                       inputs, state, smu, ssig, sW, serev,
                       rmu, rsig, rW, rerev, vleak, gleak, cm_t,
                       in_w, in_b, out_w, out_b, out_y, out_v);
}

// Round 2
// 277.787 us; speedup vs baseline: 1.0243x; 1.0243x over previous
//
#include <hip/hip_runtime.h>

#define NIN 32
#define NU  128
#define RPB 8            // batch rows per block
#define RPT 4            // rows per thread (block = 128 units x 2 row-halves)
#define UNFOLDS 6
#define LOG2E 1.44269504088896340736f

typedef float float4v __attribute__((ext_vector_type(4)));

#define SPN (NIN * NU)   // 4096 sensory synapses
#define RPN (NU * NU)    // 16384 recurrent synapses

// ---- prologue: pack (s2, sm2, We, Wv) per synapse ----
// exp(-sigma*(v-mu)) = 2^(s2*v + sm2),  s2 = -log2e*sigma, sm2 = -s2*mu
__global__ void pack_params(const float* __restrict__ mu,
                            const float* __restrict__ sig,
                            const float* __restrict__ W,
                            const float* __restrict__ erev,
                            float4v* __restrict__ out, int n) {
    int idx = blockIdx.x * blockDim.x + threadIdx.x;
    if (idx < n) {
        float sg = sig[idx];
        float s2 = -LOG2E * sg;
        float sm2 = -s2 * mu[idx];
        float Wv = W[idx];
        float We = Wv * erev[idx];
        out[idx] = (float4v){s2, sm2, We, Wv};
    }
}

// ---- main kernel ----
// thread (j = tid&127, rh = tid>>7): unit j, rows rh*4..rh*4+3 of this block's
// 8 rows. Each thread accumulates num/den over ALL i -> no cross-reduction.
// vs is double-buffered [i][r] so reads are wave-uniform ds_read_b128
// broadcasts; 1 barrier per unfold.
template <bool PACKED>
__global__ __launch_bounds__(256, 4)
void wormnet_main(const float* __restrict__ inputs,   // [B,32]
                  const float* __restrict__ state,    // [B,128]
                  const float4v* __restrict__ sp,     // [32*128] packed
                  const float4v* __restrict__ rp,     // [128*128] packed
                  const float* __restrict__ smu, const float* __restrict__ ssig,
                  const float* __restrict__ sW,  const float* __restrict__ serev,
                  const float* __restrict__ rmu, const float* __restrict__ rsig,
                  const float* __restrict__ rW,  const float* __restrict__ rerev,
                  const float* __restrict__ vleak,
                  const float* __restrict__ gleak,
                  const float* __restrict__ cm_t,
                  const float* __restrict__ in_w, const float* __restrict__ in_b,
                  const float* __restrict__ out_w, const float* __restrict__ out_b,
                  float* __restrict__ out_y,          // [B]
                  float* __restrict__ out_v)          // [B,128]
{
    __shared__ __align__(16) float xs[NIN * RPB];     // xs[i*8 + r]
    __shared__ __align__(16) float vs[2][NU * RPB];   // vs[buf][i*8 + r]

    const int tid  = threadIdx.x;
    const int j    = tid & (NU - 1);
    const int rh   = tid >> 7;           // 0/1 (wave-uniform)
    const int r0   = rh * RPT;
    const int base = blockIdx.x * RPB;

    // stage x = inputs*in_w + in_b  (256 values, 1 per thread)
    {
        int i = tid & (NIN - 1);
        int r = tid >> 5;
        xs[i * RPB + r] = inputs[(base + r) * NIN + i] * in_w[i] + in_b[i];
    }
    // stage initial v (1024 values, 4 per thread)
    {
        #pragma unroll
        for (int k = 0; k < 4; ++k) {
            int r = rh + 2 * k;
            vs[0][j * RPB + r] = state[(base + r) * NU + j];
        }
    }
    __syncthreads();

    // ---- sensory sums over all 32 inputs for this thread's 4 rows ----
    float numS[RPT], denS[RPT];
    #pragma unroll
    for (int r = 0; r < RPT; ++r) { numS[r] = 0.0f; denS[r] = 0.0f; }

    #pragma unroll 4
    for (int i = 0; i < NIN; ++i) {
        float4v p;
        if (PACKED) {
            p = sp[i * NU + j];
        } else {
            int idx = i * NU + j;
            float sg = ssig[idx];
            float s2 = -LOG2E * sg;
            p = (float4v){s2, -s2 * smu[idx], sW[idx] * serev[idx], sW[idx]};
        }
        float4v xv = *(const float4v*)&xs[i * RPB + r0];
        #pragma unroll
        for (int r = 0; r < RPT; ++r) {
            float t = __builtin_fmaf(p.x, xv[r], p.y);
            float e = __builtin_amdgcn_exp2f(t);
            float sgm = __builtin_amdgcn_rcpf(1.0f + e);
            numS[r] = __builtin_fmaf(p.z, sgm, numS[r]);
            denS[r] = __builtin_fmaf(p.w, sgm, denS[r]);
        }
    }

    // per-unit constants + this thread's v registers
    const float cm = cm_t[j];
    const float gl = gleak[j];
    const float glvl = gl * vleak[j];
    const float cg = cm + gl;
    float vold[RPT];
    #pragma unroll
    for (int r = 0; r < RPT; ++r) vold[r] = vs[0][j * RPB + r0 + r];

    // ---- 6 semi-implicit unfolds, 1 barrier each (ping-pong vs) ----
    int cur = 0;
    for (int u = 0; u < UNFOLDS; ++u) {
        float num[RPT], den[RPT];
        #pragma unroll
        for (int r = 0; r < RPT; ++r) { num[r] = numS[r]; den[r] = denS[r]; }

        #pragma unroll 4
        for (int i = 0; i < NU; ++i) {
            float4v p;
            if (PACKED) {
                p = rp[i * NU + j];
            } else {
                int idx = i * NU + j;
                float sg = rsig[idx];
                float s2 = -LOG2E * sg;
                p = (float4v){s2, -s2 * rmu[idx], rW[idx] * rerev[idx], rW[idx]};
            }
            float4v vv = *(const float4v*)&vs[cur][i * RPB + r0];
            #pragma unroll
            for (int r = 0; r < RPT; ++r) {
                float t = __builtin_fmaf(p.x, vv[r], p.y);
                float e = __builtin_amdgcn_exp2f(t);
                float sgm = __builtin_amdgcn_rcpf(1.0f + e);
                num[r] = __builtin_fmaf(p.z, sgm, num[r]);
                den[r] = __builtin_fmaf(p.w, sgm, den[r]);
            }
        }

        float4v vnew;
        #pragma unroll
        for (int r = 0; r < RPT; ++r) {
            float tn = __builtin_fmaf(cm, vold[r], glvl) + num[r];
            float td = cg + den[r];
            float vn = tn * __builtin_amdgcn_rcpf(td);
            vold[r] = vn;
            vnew[r] = vn;
        }
        *(float4v*)&vs[cur ^ 1][j * RPB + r0] = vnew;
        __syncthreads();
        cur ^= 1;
    }

    // ---- epilogue ----
    #pragma unroll
    for (int r = 0; r < RPT; ++r) {
        out_v[(base + r0 + r) * NU + j] = vold[r];
    }
    if (j == 0) {
        const float ow = out_w[0], ob = out_b[0];
        #pragma unroll
        for (int r = 0; r < RPT; ++r) {
            out_y[base + r0 + r] = __builtin_fmaf(vold[r], ow, ob);
        }
    }
}

extern "C" void kernel_launch(void* const* d_in, const int* in_sizes, int n_in,
                              void* d_out, int out_size, void* d_ws, size_t ws_size,
                              hipStream_t stream) {
    const float* inputs  = (const float*)d_in[0];
    const float* state   = (const float*)d_in[1];
    const float* smu     = (const float*)d_in[2];
    const float* ssig    = (const float*)d_in[3];
    const float* sW      = (const float*)d_in[4];
    const float* serev   = (const float*)d_in[5];
    const float* rmu     = (const float*)d_in[6];
    const float* rsig    = (const float*)d_in[7];
    const float* rW      = (const float*)d_in[8];
    const float* rerev   = (const float*)d_in[9];
    const float* vleak   = (const float*)d_in[10];
    const float* gleak   = (const float*)d_in[11];
    const float* cm_t    = (const float*)d_in[12];
    const float* in_w    = (const float*)d_in[13];
    const float* in_b    = (const float*)d_in[14];
    const float* out_w   = (const float*)d_in[15];
    const float* out_b   = (const float*)d_in[16];

    const int batch = in_sizes[1] / NU;        // 8192
    float* out_y = (float*)d_out;              // [batch]
    float* out_v = (float*)d_out + batch;      // [batch,128]

    const size_t need = (size_t)(SPN + RPN) * sizeof(float4v);  // 320 KB
    const bool packed = ws_size >= need;
    float4v* sp = (float4v*)d_ws;
    float4v* rp = sp + SPN;

    if (packed) {
        hipLaunchKernelGGL(pack_params, dim3((SPN + 255) / 256), dim3(256), 0, stream,
                           smu, ssig, sW, serev, sp, SPN);
        hipLaunchKernelGGL(pack_params, dim3((RPN + 255) / 256), dim3(256), 0, stream,
                           rmu, rsig, rW, rerev, rp, RPN);
    }

    dim3 grid(batch / RPB), block(256);
    if (packed) {
        hipLaunchKernelGGL((wormnet_main<true>), grid, block, 0, stream,
                           inputs, state, sp, rp,
                           smu, ssig, sW, serev, rmu, rsig, rW, rerev,
                           vleak, gleak, cm_t, in_w, in_b, out_w, out_b,
                           out_y, out_v);
    } else {
        hipLaunchKernelGGL((wormnet_main<false>), grid, block, 0, stream,
                           inputs, state, sp, rp,
                           smu, ssig, sW, serev, rmu, rsig, rW, rerev,
                           vleak, gleak, cm_t, in_w, in_b, out_w, out_b,
                           out_y, out_v);
    }
}

// Round 3
// 277.273 us; speedup vs baseline: 1.0262x; 1.0019x over previous
//
#include <hip/hip_runtime.h>

#define NIN 32
#define NU  128
#define RPB 16           // batch rows per block
#define RPT 8            // rows per thread (block = 128 units x 2 row-halves)
#define UNFOLDS 6
#define LOG2E 1.44269504088896340736f

typedef float float4v __attribute__((ext_vector_type(4)));

#define SPN (NIN * NU)   // 4096 sensory synapses
#define RPN (NU * NU)    // 16384 recurrent synapses

// ---- prologue: pack (s2, sm2, We, Wv) per synapse ----
// exp(-sigma*(v-mu)) = 2^(s2*v + sm2),  s2 = -log2e*sigma, sm2 = -s2*mu
__global__ void pack_params(const float* __restrict__ mu,
                            const float* __restrict__ sig,
                            const float* __restrict__ W,
                            const float* __restrict__ erev,
                            float4v* __restrict__ out, int n) {
    int idx = blockIdx.x * blockDim.x + threadIdx.x;
    if (idx < n) {
        float sg = sig[idx];
        float s2 = -LOG2E * sg;
        float sm2 = -s2 * mu[idx];
        float Wv = W[idx];
        float We = Wv * erev[idx];
        out[idx] = (float4v){s2, sm2, We, Wv};
    }
}

// Per-eval sigmoid with 2-way shared rcp:
//   a_r = 1 + 2^(s2*v_r + sm2);  rq = rcp(a0*a1);  s0 = rq*a1; s1 = rq*a0
// Trans ops per eval: 1 exp2 + 0.5 rcp (vs 1+1).
__global__ __launch_bounds__(256, 2)
void wormnet_main(const float* __restrict__ inputs,   // [B,32]
                  const float* __restrict__ state,    // [B,128]
                  const float4v* __restrict__ sp,     // [32*128] packed
                  const float4v* __restrict__ rp,     // [128*128] packed
                  const float* __restrict__ vleak,
                  const float* __restrict__ gleak,
                  const float* __restrict__ cm_t,
                  const float* __restrict__ in_w, const float* __restrict__ in_b,
                  const float* __restrict__ out_w, const float* __restrict__ out_b,
                  float* __restrict__ out_y,          // [B]
                  float* __restrict__ out_v)          // [B,128]
{
    __shared__ __align__(16) float xs[NIN * RPB];     // xs[i*16 + r]
    __shared__ __align__(16) float vs[2][NU * RPB];   // vs[buf][i*16 + r]

    const int tid  = threadIdx.x;
    const int j    = tid & (NU - 1);
    const int rh   = tid >> 7;            // 0/1 (wave-uniform)
    const int r0   = rh * RPT;
    const int base = blockIdx.x * RPB;

    // stage x = inputs*in_w + in_b  (512 values, 2 per thread)
    {
        int i = tid & (NIN - 1);
        int r = tid >> 5;                 // 0..7
        xs[i * RPB + r]     = inputs[(base + r) * NIN + i] * in_w[i] + in_b[i];
        xs[i * RPB + r + 8] = inputs[(base + r + 8) * NIN + i] * in_w[i] + in_b[i];
    }
    // stage initial v (2048 values, 8 per thread, coalesced over j)
    {
        #pragma unroll
        for (int r = 0; r < RPT; ++r) {
            vs[0][j * RPB + r0 + r] = state[(base + r0 + r) * NU + j];
        }
    }
    __syncthreads();

    // ---- sensory sums over all 32 inputs for this thread's 8 rows ----
    float numS[RPT], denS[RPT];
    #pragma unroll
    for (int r = 0; r < RPT; ++r) { numS[r] = 0.0f; denS[r] = 0.0f; }

    {
        const float4v* pp = sp + j;
        #pragma unroll 2
        for (int i = 0; i < NIN; ++i) {
            float4v p = pp[0]; pp += NU;
            float4v xa = *(const float4v*)&xs[i * RPB + r0];
            float4v xb = *(const float4v*)&xs[i * RPB + r0 + 4];
            float a[RPT];
            #pragma unroll
            for (int r = 0; r < 4; ++r) {
                a[r]     = 1.0f + __builtin_amdgcn_exp2f(__builtin_fmaf(p.x, xa[r], p.y));
                a[r + 4] = 1.0f + __builtin_amdgcn_exp2f(__builtin_fmaf(p.x, xb[r], p.y));
            }
            #pragma unroll
            for (int q = 0; q < RPT / 2; ++q) {
                float rq = __builtin_amdgcn_rcpf(a[2*q] * a[2*q+1]);
                float s0 = rq * a[2*q+1];
                float s1 = rq * a[2*q];
                numS[2*q]   = __builtin_fmaf(p.z, s0, numS[2*q]);
                denS[2*q]   = __builtin_fmaf(p.w, s0, denS[2*q]);
                numS[2*q+1] = __builtin_fmaf(p.z, s1, numS[2*q+1]);
                denS[2*q+1] = __builtin_fmaf(p.w, s1, denS[2*q+1]);
            }
        }
    }

    // per-unit constants + this thread's v registers
    const float cm = cm_t[j];
    const float gl = gleak[j];
    const float glvl = gl * vleak[j];
    const float cg = cm + gl;
    float vold[RPT];
    #pragma unroll
    for (int r = 0; r < RPT; ++r) vold[r] = vs[0][j * RPB + r0 + r];

    // ---- 6 semi-implicit unfolds, 1 barrier each (ping-pong vs) ----
    int cur = 0;
    for (int u = 0; u < UNFOLDS; ++u) {
        float num[RPT], den[RPT];
        #pragma unroll
        for (int r = 0; r < RPT; ++r) { num[r] = numS[r]; den[r] = denS[r]; }

        const float4v* pp = rp + j;
        #pragma unroll 2
        for (int i = 0; i < NU; ++i) {
            float4v p = pp[0]; pp += NU;
            float4v va = *(const float4v*)&vs[cur][i * RPB + r0];
            float4v vb = *(const float4v*)&vs[cur][i * RPB + r0 + 4];
            float a[RPT];
            #pragma unroll
            for (int r = 0; r < 4; ++r) {
                a[r]     = 1.0f + __builtin_amdgcn_exp2f(__builtin_fmaf(p.x, va[r], p.y));
                a[r + 4] = 1.0f + __builtin_amdgcn_exp2f(__builtin_fmaf(p.x, vb[r], p.y));
            }
            #pragma unroll
            for (int q = 0; q < RPT / 2; ++q) {
                float rq = __builtin_amdgcn_rcpf(a[2*q] * a[2*q+1]);
                float s0 = rq * a[2*q+1];
                float s1 = rq * a[2*q];
                num[2*q]   = __builtin_fmaf(p.z, s0, num[2*q]);
                den[2*q]   = __builtin_fmaf(p.w, s0, den[2*q]);
                num[2*q+1] = __builtin_fmaf(p.z, s1, num[2*q+1]);
                den[2*q+1] = __builtin_fmaf(p.w, s1, den[2*q+1]);
            }
        }

        #pragma unroll
        for (int r = 0; r < RPT; ++r) {
            float tn = __builtin_fmaf(cm, vold[r], glvl) + num[r];
            float td = cg + den[r];
            float vn = tn * __builtin_amdgcn_rcpf(td);
            vold[r] = vn;
            vs[cur ^ 1][j * RPB + r0 + r] = vn;
        }
        __syncthreads();
        cur ^= 1;
    }

    // ---- epilogue ----
    #pragma unroll
    for (int r = 0; r < RPT; ++r) {
        out_v[(base + r0 + r) * NU + j] = vold[r];
    }
    if (j == 0) {
        const float ow = out_w[0], ob = out_b[0];
        #pragma unroll
        for (int r = 0; r < RPT; ++r) {
            out_y[base + r0 + r] = __builtin_fmaf(vold[r], ow, ob);
        }
    }
}

extern "C" void kernel_launch(void* const* d_in, const int* in_sizes, int n_in,
                              void* d_out, int out_size, void* d_ws, size_t ws_size,
                              hipStream_t stream) {
    const float* inputs  = (const float*)d_in[0];
    const float* state   = (const float*)d_in[1];
    const float* smu     = (const float*)d_in[2];
    const float* ssig    = (const float*)d_in[3];
    const float* sW      = (const float*)d_in[4];
    const float* serev   = (const float*)d_in[5];
    const float* rmu     = (const float*)d_in[6];
    const float* rsig    = (const float*)d_in[7];
    const float* rW      = (const float*)d_in[8];
    const float* rerev   = (const float*)d_in[9];
    const float* vleak   = (const float*)d_in[10];
    const float* gleak   = (const float*)d_in[11];
    const float* cm_t    = (const float*)d_in[12];
    const float* in_w    = (const float*)d_in[13];
    const float* in_b    = (const float*)d_in[14];
    const float* out_w   = (const float*)d_in[15];
    const float* out_b   = (const float*)d_in[16];

    const int batch = in_sizes[1] / NU;        // 8192
    float* out_y = (float*)d_out;              // [batch]
    float* out_v = (float*)d_out + batch;      // [batch,128]

    float4v* sp = (float4v*)d_ws;
    float4v* rp = sp + SPN;

    hipLaunchKernelGGL(pack_params, dim3((SPN + 255) / 256), dim3(256), 0, stream,
                       smu, ssig, sW, serev, sp, SPN);
    hipLaunchKernelGGL(pack_params, dim3((RPN + 255) / 256), dim3(256), 0, stream,
                       rmu, rsig, rW, rerev, rp, RPN);

    dim3 grid(batch / RPB), block(256);
    hipLaunchKernelGGL(wormnet_main, grid, block, 0, stream,
                       inputs, state, sp, rp,
                       vleak, gleak, cm_t, in_w, in_b, out_w, out_b,
                       out_y, out_v);
}

// Round 4
// 267.568 us; speedup vs baseline: 1.0634x; 1.0363x over previous
//
#include <hip/hip_runtime.h>

#define NIN 32
#define NU  128
#define RPB 8            // batch rows per block
#define NQ  4            // i-range quarters (threads per j)
#define UNFOLDS 6
#define LOG2E 1.44269504088896340736f

typedef float float4v __attribute__((ext_vector_type(4)));

#define SPN (NIN * NU)   // 4096 sensory synapses
#define RPN (NU * NU)    // 16384 recurrent synapses

// ---- prologue: pack (s2, sm2, We, Wv) per synapse ----
// exp(-sigma*(v-mu)) = 2^(s2*v + sm2),  s2 = -log2e*sigma, sm2 = -s2*mu
__global__ void pack_params(const float* __restrict__ mu,
                            const float* __restrict__ sig,
                            const float* __restrict__ W,
                            const float* __restrict__ erev,
                            float4v* __restrict__ out, int n) {
    int idx = blockIdx.x * blockDim.x + threadIdx.x;
    if (idx < n) {
        float sg = sig[idx];
        float s2 = -LOG2E * sg;
        float sm2 = -s2 * mu[idx];
        float Wv = W[idx];
        float We = Wv * erev[idx];
        out[idx] = (float4v){s2, sm2, We, Wv};
    }
}

// block = 512 threads: j = tid&127 (unit), q = tid>>7 (i-quarter, wave-uniform).
// 8 batch rows per block; every thread accumulates num/den partials for its
// i-quarter over all 8 rows, partials reduced via LDS each unfold; thread
// (j,q) owns the v-update for rows q*2, q*2+1. 8 waves/SIMD (HW cap).
__global__ __launch_bounds__(512, 8)
void wormnet_main(const float* __restrict__ inputs,   // [B,32]
                  const float* __restrict__ state,    // [B,128]
                  const float4v* __restrict__ sp,     // [32*128] packed
                  const float4v* __restrict__ rp,     // [128*128] packed
                  const float* __restrict__ vleak,
                  const float* __restrict__ gleak,
                  const float* __restrict__ cm_t,
                  const float* __restrict__ in_w, const float* __restrict__ in_b,
                  const float* __restrict__ out_w, const float* __restrict__ out_b,
                  float* __restrict__ out_y,          // [B]
                  float* __restrict__ out_v)          // [B,128]
{
    __shared__ __align__(16) float xs[NIN * RPB];       // xs[i*8 + r]      1 KB
    __shared__ __align__(16) float vs[NU * RPB];        // vs[i*8 + r]      4 KB
    __shared__ float rn[RPB][NQ][NU];                   // num partials    16 KB
    __shared__ float rd[RPB][NQ][NU];                   // den partials    16 KB

    const int tid  = threadIdx.x;
    const int j    = tid & (NU - 1);
    const int q    = tid >> 7;            // 0..3, wave-uniform
    const int base = blockIdx.x * RPB;
    const int u0   = q * 2;               // this thread's update rows

    // stage x = inputs*in_w + in_b (256 values; first 256 threads)
    if (tid < NIN * RPB) {
        int i = tid & (NIN - 1);
        int r = tid >> 5;
        xs[i * RPB + r] = inputs[(base + r) * NIN + i] * in_w[i] + in_b[i];
    }
    // stage initial v (1024 values, 2 per thread: this thread's update rows)
    float vold[2];
    #pragma unroll
    for (int k = 0; k < 2; ++k) {
        float v = state[(base + u0 + k) * NU + j];
        vold[k] = v;
        vs[j * RPB + u0 + k] = v;
    }
    __syncthreads();

    // ---- sensory partial sums over i-quarter [q*8, q*8+8), all 8 rows ----
    float numS[RPB], denS[RPB];
    #pragma unroll
    for (int r = 0; r < RPB; ++r) { numS[r] = 0.0f; denS[r] = 0.0f; }
    {
        const float4v* pp = sp + q * (NIN / NQ) * NU + j;
        #pragma unroll 2
        for (int ii = 0; ii < NIN / NQ; ++ii) {
            const int i = q * (NIN / NQ) + ii;
            float4v p = pp[0]; pp += NU;
            float4v xa = *(const float4v*)&xs[i * RPB];
            float4v xb = *(const float4v*)&xs[i * RPB + 4];
            float a[RPB];
            #pragma unroll
            for (int r = 0; r < 4; ++r) {
                a[r]     = 1.0f + __builtin_amdgcn_exp2f(__builtin_fmaf(p.x, xa[r], p.y));
                a[r + 4] = 1.0f + __builtin_amdgcn_exp2f(__builtin_fmaf(p.x, xb[r], p.y));
            }
            #pragma unroll
            for (int w = 0; w < RPB / 2; ++w) {
                float rq = __builtin_amdgcn_rcpf(a[2*w] * a[2*w+1]);
                float s0 = rq * a[2*w+1];
                float s1 = rq * a[2*w];
                numS[2*w]   = __builtin_fmaf(p.z, s0, numS[2*w]);
                denS[2*w]   = __builtin_fmaf(p.w, s0, denS[2*w]);
                numS[2*w+1] = __builtin_fmaf(p.z, s1, numS[2*w+1]);
                denS[2*w+1] = __builtin_fmaf(p.w, s1, denS[2*w+1]);
            }
        }
    }

    // per-unit constants
    const float cm = cm_t[j];
    const float gl = gleak[j];
    const float glvl = gl * vleak[j];
    const float cg = cm + gl;

    // ---- 6 semi-implicit unfolds ----
    for (int u = 0; u < UNFOLDS; ++u) {
        float num[RPB], den[RPB];
        #pragma unroll
        for (int r = 0; r < RPB; ++r) { num[r] = numS[r]; den[r] = denS[r]; }

        const float4v* pp = rp + q * (NU / NQ) * NU + j;
        #pragma unroll 2
        for (int ii = 0; ii < NU / NQ; ++ii) {
            const int i = q * (NU / NQ) + ii;
            float4v p = pp[0]; pp += NU;
            float4v va = *(const float4v*)&vs[i * RPB];
            float4v vb = *(const float4v*)&vs[i * RPB + 4];
            float a[RPB];
            #pragma unroll
            for (int r = 0; r < 4; ++r) {
                a[r]     = 1.0f + __builtin_amdgcn_exp2f(__builtin_fmaf(p.x, va[r], p.y));
                a[r + 4] = 1.0f + __builtin_amdgcn_exp2f(__builtin_fmaf(p.x, vb[r], p.y));
            }
            #pragma unroll
            for (int w = 0; w < RPB / 2; ++w) {
                float rq = __builtin_amdgcn_rcpf(a[2*w] * a[2*w+1]);
                float s0 = rq * a[2*w+1];
                float s1 = rq * a[2*w];
                num[2*w]   = __builtin_fmaf(p.z, s0, num[2*w]);
                den[2*w]   = __builtin_fmaf(p.w, s0, den[2*w]);
                num[2*w+1] = __builtin_fmaf(p.z, s1, num[2*w+1]);
                den[2*w+1] = __builtin_fmaf(p.w, s1, den[2*w+1]);
            }
        }

        // publish partials (coalesced over j, conflict-free)
        #pragma unroll
        for (int r = 0; r < RPB; ++r) {
            rn[r][q][j] = num[r];
            rd[r][q][j] = den[r];
        }
        __syncthreads();

        // update this thread's 2 rows
        #pragma unroll
        for (int k = 0; k < 2; ++k) {
            const int r = u0 + k;
            float tn = rn[r][0][j] + rn[r][1][j] + rn[r][2][j] + rn[r][3][j];
            float td = rd[r][0][j] + rd[r][1][j] + rd[r][2][j] + rd[r][3][j];
            float vn = (__builtin_fmaf(cm, vold[k], glvl) + tn)
                       * __builtin_amdgcn_rcpf(cg + td);
            vold[k] = vn;
            vs[j * RPB + r] = vn;
        }
        __syncthreads();
    }

    // ---- epilogue: thread (j,q) writes its 2 rows (coalesced over j) ----
    #pragma unroll
    for (int k = 0; k < 2; ++k) {
        out_v[(base + u0 + k) * NU + j] = vold[k];
    }
    if (j == 0) {
        const float ow = out_w[0], ob = out_b[0];
        #pragma unroll
        for (int k = 0; k < 2; ++k) {
            out_y[base + u0 + k] = __builtin_fmaf(vold[k], ow, ob);
        }
    }
}

extern "C" void kernel_launch(void* const* d_in, const int* in_sizes, int n_in,
                              void* d_out, int out_size, void* d_ws, size_t ws_size,
                              hipStream_t stream) {
    const float* inputs  = (const float*)d_in[0];
    const float* state   = (const float*)d_in[1];
    const float* smu     = (const float*)d_in[2];
    const float* ssig    = (const float*)d_in[3];
    const float* sW      = (const float*)d_in[4];
    const float* serev   = (const float*)d_in[5];
    const float* rmu     = (const float*)d_in[6];
    const float* rsig    = (const float*)d_in[7];
    const float* rW      = (const float*)d_in[8];
    const float* rerev   = (const float*)d_in[9];
    const float* vleak   = (const float*)d_in[10];
    const float* gleak   = (const float*)d_in[11];
    const float* cm_t    = (const float*)d_in[12];
    const float* in_w    = (const float*)d_in[13];
    const float* in_b    = (const float*)d_in[14];
    const float* out_w   = (const float*)d_in[15];
    const float* out_b   = (const float*)d_in[16];

    const int batch = in_sizes[1] / NU;        // 8192
    float* out_y = (float*)d_out;              // [batch]
    float* out_v = (float*)d_out + batch;      // [batch,128]

    float4v* sp = (float4v*)d_ws;
    float4v* rp = sp + SPN;

    hipLaunchKernelGGL(pack_params, dim3((SPN + 255) / 256), dim3(256), 0, stream,
                       smu, ssig, sW, serev, sp, SPN);
    hipLaunchKernelGGL(pack_params, dim3((RPN + 255) / 256), dim3(256), 0, stream,
                       rmu, rsig, rW, rerev, rp, RPN);

    dim3 grid(batch / RPB), block(NU * NQ);    // 1024 x 512
    hipLaunchKernelGGL(wormnet_main, grid, block, 0, stream,
                       inputs, state, sp, rp,
                       vleak, gleak, cm_t, in_w, in_b, out_w, out_b,
                       out_y, out_v);
}